// Round 12
// baseline (261.649 us; speedup 1.0000x reference)
//
#include <hip/hip_runtime.h>

// -------------------------------------------------------------------------
// GCN: h1 = relu(Agg(x@W1)+b1); h2 = relu(Agg(h1@W2)+b2); out = h2@Wl+bl
// R12: consolidated serial chain (fat fusion reverted -- R11 showed aux
//      blocks inherit the GEMM's 64KB LDS and lose latency-hiding).
//      init[zero cnt || split W1/W2/Wl] -> count(+rank) -> scanM (merged
//      scan1+scan3: each block self-computes its base from cnt) -> place
//      (atomic-free) -> gemm1(SCALE+zrow) -> agg1 -> gemm2(SCALE+zrow) ->
//      agg2 -> classifier.  9 dispatches.
// -------------------------------------------------------------------------

typedef __attribute__((ext_vector_type(8))) __bf16 bf16x8;
typedef __attribute__((ext_vector_type(8))) short short8;
typedef __attribute__((ext_vector_type(4))) float f32x4;

__device__ inline float bf_lo(unsigned u) { return __uint_as_float(u << 16); }
__device__ inline float bf_hi(unsigned u) { return __uint_as_float(u & 0xffff0000u); }
__device__ inline unsigned short f2bf(float v) {
  return __builtin_bit_cast(unsigned short, (__bf16)v);
}

__device__ inline void prep_split(const float* __restrict__ W, int NN, int local,
                                  unsigned short* __restrict__ bh,
                                  unsigned short* __restrict__ bl_) {
  int nn = local >> 7, k = local & 127;
  float v = W[(size_t)k * NN + nn];
  __bf16 h = (__bf16)v;
  bh[local] = __builtin_bit_cast(unsigned short, h);
  bl_[local] = f2bf(v - (float)h);
}

// ---- init: zero cnt + split all three weights ----
__global__ void k_init(int* __restrict__ cnt, int N,
                       const float* __restrict__ W1, const float* __restrict__ W2,
                       const float* __restrict__ Wl,
                       unsigned short* __restrict__ b1h, unsigned short* __restrict__ b1l,
                       unsigned short* __restrict__ b2h, unsigned short* __restrict__ b2l,
                       unsigned short* __restrict__ blh, unsigned short* __restrict__ bll) {
  int nbz = (N + 255) / 256;
  if ((int)blockIdx.x < nbz) {
    int i = blockIdx.x * 256 + threadIdx.x;
    if (i < N) cnt[i] = 0;
  } else {
    int idx = ((int)blockIdx.x - nbz) * 256 + threadIdx.x;
    if (idx < 16384)      prep_split(W1, 128, idx, b1h, b1l);
    else if (idx < 32768) prep_split(W2, 128, idx - 16384, b2h, b2l);
    else if (idx < 40960) prep_split(Wl, 64, idx - 32768, blh, bll);
  }
}

// ---- count in-degrees + capture per-edge rank ----
__global__ void k_count(const int* __restrict__ dst, int E,
                        int* __restrict__ cnt, int* __restrict__ rank) {
  int i = blockIdx.x * blockDim.x + threadIdx.x;
  if (i < E) rank[i] = atomicAdd(&cnt[dst[i]], 1);
}

// ---- merged scan: each block self-computes base = sum(cnt[0..b*256)),
//      then local exclusive scan -> row_off, dinv ----
__global__ void k_scanM(const int* __restrict__ cnt, int n,
                        int* __restrict__ row_off, float* __restrict__ dinv) {
  __shared__ int s[256];
  __shared__ int base_s;
  int t = threadIdx.x;
  int lim = blockIdx.x * 256;

  // base: grid-stride partial sums + block reduce (cnt is L2-resident, 200KB)
  int psum = 0;
  for (int j = t; j < lim; j += 256) psum += cnt[j];
  s[t] = psum;
  __syncthreads();
  for (int off = 128; off > 0; off >>= 1) {
    if (t < off) s[t] += s[t + off];
    __syncthreads();
  }
  if (t == 0) base_s = s[0];
  __syncthreads();
  int base = base_s;
  __syncthreads();

  // local inclusive scan of this chunk
  int i = lim + t;
  int v = (i < n) ? cnt[i] : 0;
  s[t] = v;
  __syncthreads();
  for (int off = 1; off < 256; off <<= 1) {
    int u = (t >= off) ? s[t - off] : 0;
    __syncthreads();
    s[t] += u;
    __syncthreads();
  }
  int incl = s[t];
  int excl = incl - v;
  if (i < n) {
    row_off[i] = base + excl;
    dinv[i] = rsqrtf((float)(v + 1));
    if (i == n - 1) row_off[n] = base + incl;
  }
}

// ---- place: atomic-free scatter, pos = row_off[dst] + rank ----
__global__ void k_place(const int* __restrict__ src, const int* __restrict__ dst,
                        const int* __restrict__ rank, const int* __restrict__ row_off,
                        int E, int* __restrict__ edges) {
  int e = blockIdx.x * blockDim.x + threadIdx.x;
  if (e < E) {
    int d = dst[e];
    int pos = row_off[d] + rank[e];
    __builtin_nontemporal_store(src[e], &edges[pos]);
  }
}

// ------------------- MFMA GEMM: A prefetched, B in LDS -------------------
// C[M x N] = A[M x 128] @ B[128 x N], N = NT*16.
// SCALE: scale output row r by dinv[r]; block 0 also writes zero row M
// (OOB target for agg). 3-term bf16 split: hi*hi+hi*lo+lo*hi (~2^-17 rel).
template <int NT, bool A32, bool BIAS, bool OUT_BF16, bool SCALE>
__global__ __launch_bounds__(256) void gemm3(
    const void* __restrict__ Ahi_, const unsigned short* __restrict__ Alo,
    const unsigned short* __restrict__ Bhi, const unsigned short* __restrict__ Blo,
    const float* __restrict__ bias, const float* __restrict__ dinv,
    void* __restrict__ Cout, int M) {
  constexpr int K = 128;
  constexpr int NCOL = NT * 16;
  __shared__ alignas(16) unsigned short lbh[NCOL * K];
  __shared__ alignas(16) unsigned short lbl[NCOL * K];
  int t = threadIdx.x;
  int lane = t & 63, wave = t >> 6;
  int lm = lane & 15, lk = lane >> 4;
  int m_base = blockIdx.x * 128 + wave * 32;
  const short8 zero8 = {0, 0, 0, 0, 0, 0, 0, 0};

  if (SCALE && blockIdx.x == 0 && t < 64) {   // zero row M for agg OOB lanes
    *(unsigned*)&((unsigned short*)Cout)[(size_t)M * NCOL + t * 2] = 0u;
  }

  // ---- phase 1: prefetch all A fragments ----
  bf16x8 ah[2][4], al[2][4];
  if (A32) {
    const float* Af = (const float*)Ahi_;
    float4 ra[2][4][2];
#pragma unroll
    for (int mt = 0; mt < 2; ++mt) {
      int row = m_base + mt * 16 + lm;
#pragma unroll
      for (int ks = 0; ks < 4; ++ks) {
        if (row < M) {
          ra[mt][ks][0] = *(const float4*)&Af[(size_t)row * K + ks * 32 + lk * 8];
          ra[mt][ks][1] = *(const float4*)&Af[(size_t)row * K + ks * 32 + lk * 8 + 4];
        } else {
          ra[mt][ks][0] = make_float4(0.f, 0.f, 0.f, 0.f);
          ra[mt][ks][1] = make_float4(0.f, 0.f, 0.f, 0.f);
        }
      }
    }
#pragma unroll
    for (int mt = 0; mt < 2; ++mt)
#pragma unroll
      for (int ks = 0; ks < 4; ++ks) {
        float av[8] = {ra[mt][ks][0].x, ra[mt][ks][0].y, ra[mt][ks][0].z, ra[mt][ks][0].w,
                       ra[mt][ks][1].x, ra[mt][ks][1].y, ra[mt][ks][1].z, ra[mt][ks][1].w};
#pragma unroll
        for (int j = 0; j < 8; ++j) {
          __bf16 h = (__bf16)av[j];
          ah[mt][ks][j] = h;
          al[mt][ks][j] = (__bf16)(av[j] - (float)h);
        }
      }
  } else {
    const unsigned short* Ahi = (const unsigned short*)Ahi_;
#pragma unroll
    for (int mt = 0; mt < 2; ++mt) {
      int row = m_base + mt * 16 + lm;
#pragma unroll
      for (int ks = 0; ks < 4; ++ks) {
        if (row < M) {
          ah[mt][ks] = *(const bf16x8*)&Ahi[(size_t)row * K + ks * 32 + lk * 8];
          al[mt][ks] = *(const bf16x8*)&Alo[(size_t)row * K + ks * 32 + lk * 8];
        } else {
          ah[mt][ks] = __builtin_bit_cast(bf16x8, zero8);
          al[mt][ks] = __builtin_bit_cast(bf16x8, zero8);
        }
      }
    }
  }

  // ---- phase 2: cooperative B staging (XOR-swizzled 16B chunks) ----
  for (int c = t; c < NCOL * 16; c += 256) {
    int r = c >> 4, q = c & 15;
    int sq = q ^ (r & 15);
    *(short8*)&lbh[r * K + sq * 8] = *(const short8*)&Bhi[r * K + q * 8];
    *(short8*)&lbl[r * K + sq * 8] = *(const short8*)&Blo[r * K + q * 8];
  }
  __syncthreads();

  // ---- phase 3: pure LDS + MFMA ----
  f32x4 acc[2][NT] = {};
#pragma unroll
  for (int ks = 0; ks < 4; ++ks) {
    int chunk = ks * 4 + lk;
    bf16x8 bh[NT], bl[NT];
#pragma unroll
    for (int nt = 0; nt < NT; ++nt) {
      int r = nt * 16 + lm;
      int sq = chunk ^ lm;
      bh[nt] = *(const bf16x8*)&lbh[r * K + sq * 8];
      bl[nt] = *(const bf16x8*)&lbl[r * K + sq * 8];
    }
#pragma unroll
    for (int mt = 0; mt < 2; ++mt)
#pragma unroll
      for (int nt = 0; nt < NT; ++nt) {
        acc[mt][nt] = __builtin_amdgcn_mfma_f32_16x16x32_bf16(ah[mt][ks], bh[nt], acc[mt][nt], 0, 0, 0);
        acc[mt][nt] = __builtin_amdgcn_mfma_f32_16x16x32_bf16(ah[mt][ks], bl[nt], acc[mt][nt], 0, 0, 0);
        acc[mt][nt] = __builtin_amdgcn_mfma_f32_16x16x32_bf16(al[mt][ks], bh[nt], acc[mt][nt], 0, 0, 0);
      }
  }

  // ---- epilogue: row = lk*4 + r, col = lm within each 16x16 tile ----
#pragma unroll
  for (int mt = 0; mt < 2; ++mt) {
#pragma unroll
    for (int r = 0; r < 4; ++r) {
      int row = m_base + mt * 16 + lk * 4 + r;
      if (row < M) {
        float dr = SCALE ? dinv[row] : 1.f;
#pragma unroll
        for (int nt = 0; nt < NT; ++nt) {
          int col = nt * 16 + lm;
          float v = acc[mt][nt][r];
          if (SCALE) v *= dr;
          if (BIAS) v += bias[col];
          if (OUT_BF16)
            ((unsigned short*)Cout)[(size_t)row * NCOL + col] = f2bf(v);
          else
            __builtin_nontemporal_store(v, &((float*)Cout)[(size_t)row * NCOL + col]);
        }
      }
    }
  }
}

// ------------------- aggregation: 4 edges x 16 lanes x 16B, 4B edges -------------------
// rows pre-scaled by dinv[src]; agg_i = dinv_i*(sum + self) + bias, relu.
// OOB edge slots read zero row M (index n).
__global__ __launch_bounds__(256) void k_agg(const unsigned short* __restrict__ t,
                      const int* __restrict__ row_off,
                      const int* __restrict__ edges,
                      const float* __restrict__ dinv, const float* __restrict__ bias,
                      unsigned short* __restrict__ ghi, unsigned short* __restrict__ glo,
                      int n) {
  int wave = threadIdx.x >> 6;
  int lane = threadIdx.x & 63;
  int g = lane >> 4;
  int fl = lane & 15;          // features fl*8 .. fl*8+7
  int node = blockIdx.x * 4 + wave;
  if (node >= n) return;
  int2 ro = *(const int2*)&row_off[node];
  int e0 = ro.x, e1 = ro.y;
  int last = e1 - 1;

  float acc[8] = {};
  for (int base = e0; base < e1; base += 8) {
    int i0 = base + g, i1 = base + 4 + g;
    int s0 = edges[i0 < e1 ? i0 : last];
    int s1 = edges[i1 < e1 ? i1 : last];
    s0 = i0 < e1 ? s0 : n;     // zero row
    s1 = i1 < e1 ? s1 : n;
    uint4 u0 = *(const uint4*)&t[(size_t)s0 * 128 + fl * 8];
    uint4 u1 = *(const uint4*)&t[(size_t)s1 * 128 + fl * 8];
    acc[0] += bf_lo(u0.x) + bf_lo(u1.x);
    acc[1] += bf_hi(u0.x) + bf_hi(u1.x);
    acc[2] += bf_lo(u0.y) + bf_lo(u1.y);
    acc[3] += bf_hi(u0.y) + bf_hi(u1.y);
    acc[4] += bf_lo(u0.z) + bf_lo(u1.z);
    acc[5] += bf_hi(u0.z) + bf_hi(u1.z);
    acc[6] += bf_lo(u0.w) + bf_lo(u1.w);
    acc[7] += bf_hi(u0.w) + bf_hi(u1.w);
  }
#pragma unroll
  for (int j = 0; j < 8; ++j) {
    acc[j] += __shfl_xor(acc[j], 16);
    acc[j] += __shfl_xor(acc[j], 32);
  }
  if (g == 0) {
    float di = dinv[node];
    uint4 sv = *(const uint4*)&t[(size_t)node * 128 + fl * 8];
    acc[0] += bf_lo(sv.x); acc[1] += bf_hi(sv.x);
    acc[2] += bf_lo(sv.y); acc[3] += bf_hi(sv.y);
    acc[4] += bf_lo(sv.z); acc[5] += bf_hi(sv.z);
    acc[6] += bf_lo(sv.w); acc[7] += bf_hi(sv.w);
    float4 bb0 = *(const float4*)&bias[fl * 8];
    float4 bb1 = *(const float4*)&bias[fl * 8 + 4];
    float bb[8] = {bb0.x, bb0.y, bb0.z, bb0.w, bb1.x, bb1.y, bb1.z, bb1.w};
    short8 ho, lo_;
#pragma unroll
    for (int j = 0; j < 8; ++j) {
      float s = fmaxf(acc[j] * di + bb[j], 0.f);
      __bf16 h = (__bf16)s;
      ho[j] = __builtin_bit_cast(short, h);
      lo_[j] = (short)f2bf(s - (float)h);
    }
    *(short8*)&ghi[(size_t)node * 128 + fl * 8] = ho;
    *(short8*)&glo[(size_t)node * 128 + fl * 8] = lo_;
  }
}

extern "C" void kernel_launch(void* const* d_in, const int* in_sizes, int n_in,
                              void* d_out, int out_size, void* d_ws, size_t ws_size,
                              hipStream_t stream) {
  const float* x  = (const float*)d_in[0];
  const int*   ei = (const int*)d_in[1];
  const float* W1 = (const float*)d_in[2];
  const float* b1 = (const float*)d_in[3];
  const float* W2 = (const float*)d_in[4];
  const float* b2 = (const float*)d_in[5];
  const float* Wl = (const float*)d_in[6];
  const float* bl = (const float*)d_in[7];
  float* out = (float*)d_out;

  const int D = 128;
  int N = in_sizes[0] / D;
  int E = in_sizes[1] / 2;
  const int* src = ei;
  const int* dst = ei + E;

  uintptr_t ws = (uintptr_t)d_ws;
  auto take = [&](size_t bytes) {
    uintptr_t p = ws;
    ws += (bytes + 15) & ~(size_t)15;
    return p;
  };
  unsigned short* t_bf = (unsigned short*)take(((size_t)N + 1) * D * 2);  // + zero row
  unsigned short* xh   = (unsigned short*)take((size_t)N * D * 2);
  unsigned short* xl   = (unsigned short*)take((size_t)N * D * 2);
  int*   edges   = (int*)take((size_t)E * 4);
  int*   rank    = (int*)take((size_t)E * 4);
  int*   cnt     = (int*)take((size_t)N * sizeof(int));
  int*   row_off = (int*)take(((size_t)N + 1) * sizeof(int));
  float* dinv    = (float*)take((size_t)N * sizeof(float));
  unsigned short* b1h = (unsigned short*)take(128 * 128 * 2);
  unsigned short* b1l = (unsigned short*)take(128 * 128 * 2);
  unsigned short* b2h = (unsigned short*)take(128 * 128 * 2);
  unsigned short* b2l = (unsigned short*)take(128 * 128 * 2);
  unsigned short* blh = (unsigned short*)take(128 * 64 * 2);
  unsigned short* bll = (unsigned short*)take(128 * 64 * 2);

  int nb_n = (N + 255) / 256;            // 196
  int nb_e = (E + 255) / 256;            // 2500
  int gemm_blocks = (N + 127) / 128;     // 391
  int agg_blocks = (N + 3) / 4;

  // 1) init: zero cnt + split W1/W2/Wl
  k_init<<<nb_n + 160, 256, 0, stream>>>(cnt, N, W1, W2, Wl,
                                         b1h, b1l, b2h, b2l, blh, bll);
  // 2) count + rank capture
  k_count<<<nb_e, 256, 0, stream>>>(dst, E, cnt, rank);
  // 3) merged scan -> row_off, dinv
  k_scanM<<<nb_n, 256, 0, stream>>>(cnt, N, row_off, dinv);
  // 4) place (atomic-free)
  k_place<<<nb_e, 256, 0, stream>>>(src, dst, rank, row_off, E, edges);
  // 5) layer-1 GEMM (A = fp32 x, split in-register; SCALE + zero row)
  gemm3<8, true, false, true, true><<<gemm_blocks, 256, 0, stream>>>(
      x, nullptr, b1h, b1l, nullptr, dinv, t_bf, N);
  // 6) layer-1 aggregation
  k_agg<<<agg_blocks, 256, 0, stream>>>(t_bf, row_off, edges, dinv, b1, xh, xl, N);
  // 7) layer-2 GEMM (SCALE + zero row)
  gemm3<8, false, false, true, true><<<gemm_blocks, 256, 0, stream>>>(
      xh, xl, b2h, b2l, nullptr, dinv, t_bf, N);
  // 8) layer-2 aggregation
  k_agg<<<agg_blocks, 256, 0, stream>>>(t_bf, row_off, edges, dinv, b2, xh, xl, N);
  // 9) classifier
  gemm3<4, false, true, false, false><<<gemm_blocks, 256, 0, stream>>>(
      xh, xl, blh, bll, bl, nullptr, out, N);
}

// Round 13
// 234.620 us; speedup vs baseline: 1.1152x; 1.1152x over previous
//
#include <hip/hip_runtime.h>

// -------------------------------------------------------------------------
// GCN: h1 = relu(Agg(x@W1)+b1); h2 = relu(Agg(h1@W2)+b2); out = h2@Wl+bl
// FINAL (= R10, measured best 235us):
//   memset(cnt) -> count(+rank capture) -> scan1_prepW -> scan3 ->
//   place(atomic-free) -> gemm1(SCALE+zrow) -> agg1 -> gemm2(SCALE+zrow) ->
//   agg2 -> classifier.
// Key mechanisms (all counter-verified this session):
//   - GEMMs: bf16x3-split MFMA (hi*hi+hi*lo+lo*hi, ~2^-17 rel err), B
//     pre-split/transposed staged in LDS XOR-swizzled, A fragments
//     prefetched; dinv row-scaling fused into epilogue.
//   - CSR build: rank captured from count's atomicAdd return; place is
//     atomic-free (pos = row_off[dst] + rank[e]) -- removing the
//     atomic-with-return dependency from the scatter was worth 20us (R10).
//   - agg: 4 edges x 16 lanes x 16B gather, edges are pure 4B src indices,
//     OOB lanes read a zero row; bf16 rows halve gather traffic.
//   - Failed & reverted: grid software barrier (R7: 300us spin), XCD
//     sharding (R9: neutral), fat-kernel overlap (R11: aux inherits 64KB
//     LDS, loses occupancy), merged scan (R12: O(nb^2) critical path).
// -------------------------------------------------------------------------

typedef __attribute__((ext_vector_type(8))) __bf16 bf16x8;
typedef __attribute__((ext_vector_type(8))) short short8;
typedef __attribute__((ext_vector_type(4))) float f32x4;

__device__ inline float bf_lo(unsigned u) { return __uint_as_float(u << 16); }
__device__ inline float bf_hi(unsigned u) { return __uint_as_float(u & 0xffff0000u); }
__device__ inline unsigned short f2bf(float v) {
  return __builtin_bit_cast(unsigned short, (__bf16)v);
}

// count in-degrees AND capture per-edge rank (old count value)
__global__ void k_count(const int* __restrict__ dst, int E,
                        int* __restrict__ cnt, int* __restrict__ rank) {
  int i = blockIdx.x * blockDim.x + threadIdx.x;
  if (i < E) rank[i] = atomicAdd(&cnt[dst[i]], 1);
}

// fat kernel: blocks [0, nb) do scan1 partials; [nb, nb+160) prepW
__global__ void k_scan1_prepW(const int* __restrict__ cnt, int n, int* __restrict__ partial,
                              int nb,
                              const float* __restrict__ W1, const float* __restrict__ W2,
                              const float* __restrict__ Wl,
                              unsigned short* __restrict__ b1h, unsigned short* __restrict__ b1l,
                              unsigned short* __restrict__ b2h, unsigned short* __restrict__ b2l,
                              unsigned short* __restrict__ blh, unsigned short* __restrict__ bll) {
  if ((int)blockIdx.x < nb) {
    __shared__ int s[256];
    int i = blockIdx.x * 256 + threadIdx.x;
    s[threadIdx.x] = (i < n) ? cnt[i] : 0;
    __syncthreads();
    for (int off = 128; off > 0; off >>= 1) {
      if (threadIdx.x < off) s[threadIdx.x] += s[threadIdx.x + off];
      __syncthreads();
    }
    if (threadIdx.x == 0) partial[blockIdx.x] = s[0];
  } else {
    int idx = ((int)blockIdx.x - nb) * 256 + threadIdx.x;
    const float* W;
    unsigned short *bh, *bl_;
    int N, local;
    if (idx < 16384)      { W = W1; bh = b1h; bl_ = b1l; N = 128; local = idx; }
    else if (idx < 32768) { W = W2; bh = b2h; bl_ = b2l; N = 128; local = idx - 16384; }
    else if (idx < 40960) { W = Wl; bh = blh; bl_ = bll; N = 64;  local = idx - 32768; }
    else return;
    int nn = local >> 7, k = local & 127;
    float v = W[(size_t)k * N + nn];
    __bf16 h = (__bf16)v;
    bh[local] = __builtin_bit_cast(unsigned short, h);
    bl_[local] = f2bf(v - (float)h);
  }
}

// scan3: block base from partials + exclusive scan -> row_off, dinv
__global__ void k_scan3(const int* __restrict__ cnt, const int* __restrict__ partial,
                        int nb, int n, int* __restrict__ row_off,
                        float* __restrict__ dinv) {
  __shared__ int s[256];
  __shared__ int base_s;
  int t = threadIdx.x;
  s[t] = (t < nb && t < (int)blockIdx.x) ? partial[t] : 0;
  __syncthreads();
  for (int off = 128; off > 0; off >>= 1) {
    if (t < off) s[t] += s[t + off];
    __syncthreads();
  }
  if (t == 0) base_s = s[0];
  __syncthreads();
  int base = base_s;
  __syncthreads();

  int i = blockIdx.x * 256 + t;
  int v = (i < n) ? cnt[i] : 0;
  s[t] = v;
  __syncthreads();
  for (int off = 1; off < 256; off <<= 1) {
    int u = (t >= off) ? s[t - off] : 0;
    __syncthreads();
    s[t] += u;
    __syncthreads();
  }
  int incl = s[t];
  int excl = incl - v;
  if (i < n) {
    row_off[i] = base + excl;
    dinv[i] = rsqrtf((float)(v + 1));
    if (i == n - 1) row_off[n] = base + incl;
  }
}

// place: NO atomics -- pos = row_off[dst] + rank (rank captured in k_count)
__global__ void k_place(const int* __restrict__ src, const int* __restrict__ dst,
                        const int* __restrict__ rank, const int* __restrict__ row_off,
                        int E, int* __restrict__ edges) {
  int e = blockIdx.x * blockDim.x + threadIdx.x;
  if (e < E) {
    int d = dst[e];
    int pos = row_off[d] + rank[e];
    __builtin_nontemporal_store(src[e], &edges[pos]);
  }
}

// ------------------- MFMA GEMM: A prefetched, B in LDS -------------------
// C[M x N] = A[M x 128] @ B[128 x N], N = NT*16.
// SCALE: multiply output row r by dinv[r] (pre-scaled rows for agg) and
// write zero row M (OOB target for agg). 3-term bf16 split (~2^-17 rel err).
template <int NT, bool A32, bool BIAS, bool OUT_BF16, bool SCALE>
__global__ __launch_bounds__(256) void gemm3(
    const void* __restrict__ Ahi_, const unsigned short* __restrict__ Alo,
    const unsigned short* __restrict__ Bhi, const unsigned short* __restrict__ Blo,
    const float* __restrict__ bias, const float* __restrict__ dinv,
    void* __restrict__ Cout, int M) {
  constexpr int K = 128;
  constexpr int NCOL = NT * 16;
  __shared__ alignas(16) unsigned short lbh[NCOL * K];
  __shared__ alignas(16) unsigned short lbl[NCOL * K];
  int t = threadIdx.x;
  int lane = t & 63, wave = t >> 6;
  int lm = lane & 15, lk = lane >> 4;
  int m_base = blockIdx.x * 128 + wave * 32;
  const short8 zero8 = {0, 0, 0, 0, 0, 0, 0, 0};

  if (SCALE && blockIdx.x == 0 && t < 64) {   // zero row M for agg OOB lanes
    *(unsigned*)&((unsigned short*)Cout)[(size_t)M * NCOL + t * 2] = 0u;
  }

  // ---- phase 1: prefetch all A fragments ----
  bf16x8 ah[2][4], al[2][4];
  if (A32) {
    const float* Af = (const float*)Ahi_;
    float4 ra[2][4][2];
#pragma unroll
    for (int mt = 0; mt < 2; ++mt) {
      int row = m_base + mt * 16 + lm;
#pragma unroll
      for (int ks = 0; ks < 4; ++ks) {
        if (row < M) {
          ra[mt][ks][0] = *(const float4*)&Af[(size_t)row * K + ks * 32 + lk * 8];
          ra[mt][ks][1] = *(const float4*)&Af[(size_t)row * K + ks * 32 + lk * 8 + 4];
        } else {
          ra[mt][ks][0] = make_float4(0.f, 0.f, 0.f, 0.f);
          ra[mt][ks][1] = make_float4(0.f, 0.f, 0.f, 0.f);
        }
      }
    }
#pragma unroll
    for (int mt = 0; mt < 2; ++mt)
#pragma unroll
      for (int ks = 0; ks < 4; ++ks) {
        float av[8] = {ra[mt][ks][0].x, ra[mt][ks][0].y, ra[mt][ks][0].z, ra[mt][ks][0].w,
                       ra[mt][ks][1].x, ra[mt][ks][1].y, ra[mt][ks][1].z, ra[mt][ks][1].w};
#pragma unroll
        for (int j = 0; j < 8; ++j) {
          __bf16 h = (__bf16)av[j];
          ah[mt][ks][j] = h;
          al[mt][ks][j] = (__bf16)(av[j] - (float)h);
        }
      }
  } else {
    const unsigned short* Ahi = (const unsigned short*)Ahi_;
#pragma unroll
    for (int mt = 0; mt < 2; ++mt) {
      int row = m_base + mt * 16 + lm;
#pragma unroll
      for (int ks = 0; ks < 4; ++ks) {
        if (row < M) {
          ah[mt][ks] = *(const bf16x8*)&Ahi[(size_t)row * K + ks * 32 + lk * 8];
          al[mt][ks] = *(const bf16x8*)&Alo[(size_t)row * K + ks * 32 + lk * 8];
        } else {
          ah[mt][ks] = __builtin_bit_cast(bf16x8, zero8);
          al[mt][ks] = __builtin_bit_cast(bf16x8, zero8);
        }
      }
    }
  }

  // ---- phase 2: cooperative B staging (XOR-swizzled 16B chunks) ----
  for (int c = t; c < NCOL * 16; c += 256) {
    int r = c >> 4, q = c & 15;
    int sq = q ^ (r & 15);
    *(short8*)&lbh[r * K + sq * 8] = *(const short8*)&Bhi[r * K + q * 8];
    *(short8*)&lbl[r * K + sq * 8] = *(const short8*)&Blo[r * K + q * 8];
  }
  __syncthreads();

  // ---- phase 3: pure LDS + MFMA ----
  f32x4 acc[2][NT] = {};
#pragma unroll
  for (int ks = 0; ks < 4; ++ks) {
    int chunk = ks * 4 + lk;
    bf16x8 bh[NT], bl[NT];
#pragma unroll
    for (int nt = 0; nt < NT; ++nt) {
      int r = nt * 16 + lm;
      int sq = chunk ^ lm;
      bh[nt] = *(const bf16x8*)&lbh[r * K + sq * 8];
      bl[nt] = *(const bf16x8*)&lbl[r * K + sq * 8];
    }
#pragma unroll
    for (int mt = 0; mt < 2; ++mt)
#pragma unroll
      for (int nt = 0; nt < NT; ++nt) {
        acc[mt][nt] = __builtin_amdgcn_mfma_f32_16x16x32_bf16(ah[mt][ks], bh[nt], acc[mt][nt], 0, 0, 0);
        acc[mt][nt] = __builtin_amdgcn_mfma_f32_16x16x32_bf16(ah[mt][ks], bl[nt], acc[mt][nt], 0, 0, 0);
        acc[mt][nt] = __builtin_amdgcn_mfma_f32_16x16x32_bf16(al[mt][ks], bh[nt], acc[mt][nt], 0, 0, 0);
      }
  }

  // ---- epilogue: row = lk*4 + r, col = lm within each 16x16 tile ----
#pragma unroll
  for (int mt = 0; mt < 2; ++mt) {
#pragma unroll
    for (int r = 0; r < 4; ++r) {
      int row = m_base + mt * 16 + lk * 4 + r;
      if (row < M) {
        float dr = SCALE ? dinv[row] : 1.f;
#pragma unroll
        for (int nt = 0; nt < NT; ++nt) {
          int col = nt * 16 + lm;
          float v = acc[mt][nt][r];
          if (SCALE) v *= dr;
          if (BIAS) v += bias[col];
          if (OUT_BF16)
            ((unsigned short*)Cout)[(size_t)row * NCOL + col] = f2bf(v);
          else
            __builtin_nontemporal_store(v, &((float*)Cout)[(size_t)row * NCOL + col]);
        }
      }
    }
  }
}

// ------------------- aggregation: 4 edges x 16 lanes x 16B, 4B edges -------------------
// rows pre-scaled by dinv[src]; agg_i = dinv_i*(sum + self) + bias, relu.
// OOB edge slots read zero row M (index n).
__global__ __launch_bounds__(256) void k_agg(const unsigned short* __restrict__ t,
                      const int* __restrict__ row_off,
                      const int* __restrict__ edges,
                      const float* __restrict__ dinv, const float* __restrict__ bias,
                      unsigned short* __restrict__ ghi, unsigned short* __restrict__ glo,
                      int n) {
  int wave = threadIdx.x >> 6;
  int lane = threadIdx.x & 63;
  int g = lane >> 4;
  int fl = lane & 15;          // features fl*8 .. fl*8+7
  int node = blockIdx.x * 4 + wave;
  if (node >= n) return;
  int2 ro = *(const int2*)&row_off[node];
  int e0 = ro.x, e1 = ro.y;
  int last = e1 - 1;

  float acc[8] = {};
  for (int base = e0; base < e1; base += 8) {
    int i0 = base + g, i1 = base + 4 + g;
    int s0 = edges[i0 < e1 ? i0 : last];
    int s1 = edges[i1 < e1 ? i1 : last];
    s0 = i0 < e1 ? s0 : n;     // zero row
    s1 = i1 < e1 ? s1 : n;
    uint4 u0 = *(const uint4*)&t[(size_t)s0 * 128 + fl * 8];
    uint4 u1 = *(const uint4*)&t[(size_t)s1 * 128 + fl * 8];
    acc[0] += bf_lo(u0.x) + bf_lo(u1.x);
    acc[1] += bf_hi(u0.x) + bf_hi(u1.x);
    acc[2] += bf_lo(u0.y) + bf_lo(u1.y);
    acc[3] += bf_hi(u0.y) + bf_hi(u1.y);
    acc[4] += bf_lo(u0.z) + bf_lo(u1.z);
    acc[5] += bf_hi(u0.z) + bf_hi(u1.z);
    acc[6] += bf_lo(u0.w) + bf_lo(u1.w);
    acc[7] += bf_hi(u0.w) + bf_hi(u1.w);
  }
#pragma unroll
  for (int j = 0; j < 8; ++j) {
    acc[j] += __shfl_xor(acc[j], 16);
    acc[j] += __shfl_xor(acc[j], 32);
  }
  if (g == 0) {
    float di = dinv[node];
    uint4 sv = *(const uint4*)&t[(size_t)node * 128 + fl * 8];
    acc[0] += bf_lo(sv.x); acc[1] += bf_hi(sv.x);
    acc[2] += bf_lo(sv.y); acc[3] += bf_hi(sv.y);
    acc[4] += bf_lo(sv.z); acc[5] += bf_hi(sv.z);
    acc[6] += bf_lo(sv.w); acc[7] += bf_hi(sv.w);
    float4 bb0 = *(const float4*)&bias[fl * 8];
    float4 bb1 = *(const float4*)&bias[fl * 8 + 4];
    float bb[8] = {bb0.x, bb0.y, bb0.z, bb0.w, bb1.x, bb1.y, bb1.z, bb1.w};
    short8 ho, lo_;
#pragma unroll
    for (int j = 0; j < 8; ++j) {
      float s = fmaxf(acc[j] * di + bb[j], 0.f);
      __bf16 h = (__bf16)s;
      ho[j] = __builtin_bit_cast(short, h);
      lo_[j] = (short)f2bf(s - (float)h);
    }
    *(short8*)&ghi[(size_t)node * 128 + fl * 8] = ho;
    *(short8*)&glo[(size_t)node * 128 + fl * 8] = lo_;
  }
}

extern "C" void kernel_launch(void* const* d_in, const int* in_sizes, int n_in,
                              void* d_out, int out_size, void* d_ws, size_t ws_size,
                              hipStream_t stream) {
  const float* x  = (const float*)d_in[0];
  const int*   ei = (const int*)d_in[1];
  const float* W1 = (const float*)d_in[2];
  const float* b1 = (const float*)d_in[3];
  const float* W2 = (const float*)d_in[4];
  const float* b2 = (const float*)d_in[5];
  const float* Wl = (const float*)d_in[6];
  const float* bl = (const float*)d_in[7];
  float* out = (float*)d_out;

  const int D = 128;
  int N = in_sizes[0] / D;
  int E = in_sizes[1] / 2;
  const int* src = ei;
  const int* dst = ei + E;

  uintptr_t ws = (uintptr_t)d_ws;
  auto take = [&](size_t bytes) {
    uintptr_t p = ws;
    ws += (bytes + 15) & ~(size_t)15;
    return p;
  };
  unsigned short* t_bf = (unsigned short*)take(((size_t)N + 1) * D * 2);  // + zero row
  unsigned short* xh   = (unsigned short*)take((size_t)N * D * 2);
  unsigned short* xl   = (unsigned short*)take((size_t)N * D * 2);
  int*   edges   = (int*)take((size_t)E * 4);
  int*   rank    = (int*)take((size_t)E * 4);
  int*   cnt     = (int*)take((size_t)N * sizeof(int));
  int*   row_off = (int*)take(((size_t)N + 1) * sizeof(int));
  float* dinv    = (float*)take((size_t)N * sizeof(float));
  int*   partial = (int*)take(256 * sizeof(int));
  unsigned short* b1h = (unsigned short*)take(128 * 128 * 2);
  unsigned short* b1l = (unsigned short*)take(128 * 128 * 2);
  unsigned short* b2h = (unsigned short*)take(128 * 128 * 2);
  unsigned short* b2l = (unsigned short*)take(128 * 128 * 2);
  unsigned short* blh = (unsigned short*)take(128 * 64 * 2);
  unsigned short* bll = (unsigned short*)take(128 * 64 * 2);

  int nb_n = (N + 255) / 256;   // 196 (fits single-block base reduce)
  int nb_e = (E + 255) / 256;

  // ---- graph preprocessing + weight prep ----
  hipMemsetAsync(cnt, 0, (size_t)N * sizeof(int), stream);
  k_count<<<nb_e, 256, 0, stream>>>(dst, E, cnt, rank);
  k_scan1_prepW<<<nb_n + 160, 256, 0, stream>>>(cnt, N, partial, nb_n,
                                                W1, W2, Wl, b1h, b1l, b2h, b2l, blh, bll);
  k_scan3<<<nb_n, 256, 0, stream>>>(cnt, partial, nb_n, N, row_off, dinv);
  k_place<<<nb_e, 256, 0, stream>>>(src, dst, rank, row_off, E, edges);

  int gemm_blocks = (N + 127) / 128;
  int agg_blocks = (N + 3) / 4;

  // ---- layer 1 (A = fp32 x, split in-register; output pre-scaled by dinv) ----
  gemm3<8, true, false, true, true><<<gemm_blocks, 256, 0, stream>>>(
      x, nullptr, b1h, b1l, nullptr, dinv, t_bf, N);
  k_agg<<<agg_blocks, 256, 0, stream>>>(t_bf, row_off, edges, dinv, b1, xh, xl, N);
  // ---- layer 2 ----
  gemm3<8, false, false, true, true><<<gemm_blocks, 256, 0, stream>>>(
      xh, xl, b2h, b2l, nullptr, dinv, t_bf, N);
  k_agg<<<agg_blocks, 256, 0, stream>>>(t_bf, row_off, edges, dinv, b2, xh, xl, N);
  // ---- classifier ----
  gemm3<4, false, true, false, false><<<gemm_blocks, 256, 0, stream>>>(
      xh, xl, blh, bll, bl, nullptr, out, N);
}